// Round 1
// baseline (1208.129 us; speedup 1.0000x reference)
//
#include <hip/hip_runtime.h>
#include <hip/hip_fp16.h>

#define BB 32
#define SS 512
#define HH 128
#define D2 256
#define D3 384
#define D4 512

// ws layout (float offsets)
#define OFF_TK    0
#define OFF_TQ    (OFF_TK + BB*SS*HH)          // tanh(keyp) [B][S][H]
#define OFF_CT    (OFF_TQ + BB*SS*HH)          // context   [B][S][2H]
#define OFF_GI    (OFF_CT + BB*SS*D2)          // gi        [B][S][3H]
#define OFF_WTG   (OFF_GI + BB*SS*D3)          // W_g^T     [512][512]
#define OFF_WTIH  (OFF_WTG + D4*D4)            // W_ih^T    [512][384]
#define OFF_WTVP  (OFF_WTIH + D4*D3)           // W_vP^T    [256][128]
#define OFF_WTVPT (OFF_WTVP + D2*HH)           // W_vPt^T   [256][128]

typedef _Float16 h2_t __attribute__((ext_vector_type(2)));

__device__ __forceinline__ float fast_tanh(float x) {
  float ax = fabsf(x);
  float e  = __expf(-2.0f * ax);
  float t  = __fdividef(1.0f - e, 1.0f + e);
  return x < 0.0f ? -t : t;
}
__device__ __forceinline__ float sigm(float x) {
  return __fdividef(1.0f, 1.0f + __expf(-x));
}

// ---------------- K0: transpose weights into ws ----------------
__global__ __launch_bounds__(256) void k0_transpose(
    const float* __restrict__ Wg, const float* __restrict__ Wih,
    const float* __restrict__ Wvp, const float* __restrict__ Wvpt,
    float* __restrict__ ws) {
  int i = blockIdx.x * 256 + threadIdx.x;
  if (i < D4 * D4) {
    int k = i / D4, j = i % D4;
    ws[OFF_WTG + i] = Wg[j * D4 + k];
  } else if (i < D4 * D4 + D4 * D3) {
    int i2 = i - D4 * D4;
    int k = i2 / D3, j = i2 % D3;
    ws[OFF_WTIH + i2] = Wih[j * D4 + k];
  } else if (i < D4 * D4 + D4 * D3 + D2 * HH) {
    int i3 = i - D4 * D4 - D4 * D3;
    int d = i3 / HH, h = i3 % HH;
    ws[OFF_WTVP + i3] = Wvp[h * D2 + d];
  } else {
    int i4 = i - D4 * D4 - D4 * D3 - D2 * HH;
    int d = i4 / HH, h = i4 % HH;
    ws[OFF_WTVPT + i4] = Wvpt[h * D2 + d];
  }
}

// ---------------- K1: tk = tanh(vp @ WvP^T), tq = tanh(vp @ WvPt^T) ----------------
// grid: (BS/64, 2); y=0 -> tk, y=1 -> tq. 64 rows/block.
__global__ __launch_bounds__(256) void k1_keyq(const float* __restrict__ vp,
                                               float* __restrict__ ws) {
  const float* wt = ws + (blockIdx.y ? OFF_WTVPT : OFF_WTVP);
  float* outp = ws + (blockIdx.y ? OFF_TQ : OFF_TK);
  int tid = threadIdx.x;
  int hg = tid & 31, rs = tid >> 5;
  int h4 = hg * 4;
  int row0 = blockIdx.x * 64;
  for (int pass = 0; pass < 2; ++pass) {
    int rbase = row0 + pass * 32 + rs * 4;
    const float* vpr = vp + (size_t)rbase * D2;
    float acc[4][4] = {};
    #pragma unroll 4
    for (int d = 0; d < D2; ++d) {
      float4 w4 = *(const float4*)(wt + d * HH + h4);
      #pragma unroll
      for (int r = 0; r < 4; ++r) {
        float x = vpr[r * D2 + d];
        acc[r][0] = fmaf(x, w4.x, acc[r][0]);
        acc[r][1] = fmaf(x, w4.y, acc[r][1]);
        acc[r][2] = fmaf(x, w4.z, acc[r][2]);
        acc[r][3] = fmaf(x, w4.w, acc[r][3]);
      }
    }
    #pragma unroll
    for (int r = 0; r < 4; ++r) {
      float4 o;
      o.x = fast_tanh(acc[r][0]);
      o.y = fast_tanh(acc[r][1]);
      o.z = fast_tanh(acc[r][2]);
      o.w = fast_tanh(acc[r][3]);
      *(float4*)(outp + (size_t)(rbase + r) * HH + h4) = o;
    }
  }
}

// ---------------- K2: logits (rational tanh) + softmax + ct ----------------
// grid: (S/16, B). 16 t per block.
__global__ __launch_bounds__(256) void k2_attn(const float* __restrict__ vp,
                                               const int* __restrict__ lens,
                                               const float* __restrict__ wvt,
                                               float* __restrict__ ws) {
  int b = blockIdx.y;
  int len = lens[b];
  int t0 = blockIdx.x * 16;
  if (t0 >= len) return;
  int nt = min(16, len - t0);

  __shared__ float L[16][SS];      // logits -> unnormalized probs
  __shared__ float tqt[16][HH];
  __shared__ float vps[32][D2];
  __shared__ float inv_sum[16];

  int tid = threadIdx.x;
  const float* tk = ws + OFF_TK + (size_t)b * SS * HH;
  const float* tq = ws + OFF_TQ + (size_t)b * SS * HH;

  for (int idx = tid; idx < 16 * HH; idx += 256) {
    int i = idx >> 7, h = idx & 127;
    tqt[i][h] = tq[(size_t)(t0 + i) * HH + h];
  }
  __syncthreads();

  // logits: thread owns s columns {tid, tid+256}
  for (int sc = 0; sc < 2; ++sc) {
    int s = tid + sc * 256;
    if (s < len) {
      float acc[16] = {};
      const float* tkr = tk + (size_t)s * HH;
      for (int h4 = 0; h4 < 32; ++h4) {
        const float4 k4 = *(const float4*)(tkr + h4 * 4);
        const float4 w4 = *(const float4*)(wvt + h4 * 4);
        #pragma unroll
        for (int t = 0; t < 16; ++t) {
          const float4 q4 = *(const float4*)(&tqt[t][h4 * 4]);
          float n0 = k4.x + q4.x, n1 = k4.y + q4.y, n2 = k4.z + q4.z, n3 = k4.w + q4.w;
          float e0 = fmaf(k4.x, q4.x, 1.0f), e1 = fmaf(k4.y, q4.y, 1.0f);
          float e2 = fmaf(k4.z, q4.z, 1.0f), e3 = fmaf(k4.w, q4.w, 1.0f);
          float m01 = e0 * e1, m23 = e2 * e3;
          float rall = __fdividef(1.0f, m01 * m23);
          float r01 = rall * m23, r23 = rall * m01;
          float i0 = r01 * e1, i1 = r01 * e0, i2 = r23 * e3, i3 = r23 * e2;
          float a = acc[t];
          a = fmaf(w4.x, n0 * i0, a);
          a = fmaf(w4.y, n1 * i1, a);
          a = fmaf(w4.z, n2 * i2, a);
          a = fmaf(w4.w, n3 * i3, a);
          acc[t] = a;
        }
      }
      #pragma unroll
      for (int t = 0; t < 16; ++t) L[t][s] = acc[t];
    }
  }
  __syncthreads();

  // softmax (store unnormalized exp, denominators in inv_sum)
  {
    int w = tid >> 6, lane = tid & 63;
    for (int ii = 0; ii < 4; ++ii) {
      int i = w + ii * 4;
      if (i < nt) {
        float m = -1e30f;
        for (int s = lane; s < len; s += 64) m = fmaxf(m, L[i][s]);
        #pragma unroll
        for (int off = 32; off > 0; off >>= 1) m = fmaxf(m, __shfl_xor(m, off));
        float sm = 0.0f;
        for (int s = lane; s < len; s += 64) {
          float e = __expf(L[i][s] - m);
          L[i][s] = e;
          sm += e;
        }
        #pragma unroll
        for (int off = 32; off > 0; off >>= 1) sm += __shfl_xor(sm, off);
        if (lane == 0) inv_sum[i] = __fdividef(1.0f, sm);
      }
    }
  }
  __syncthreads();

  // ct[t][d] = sum_s p[t][s] * vp[b][s][d]
  int d4 = (tid & 63) * 4;
  int tg = tid >> 6;   // 4 t per group
  float4 acc4[4] = {};
  for (int s0 = 0; s0 < len; s0 += 32) {
    int ns = min(32, len - s0);
    __syncthreads();
    for (int idx = tid; idx < 32 * 64; idx += 256) {
      int r = idx >> 6, c = idx & 63;
      if (r < ns)
        *(float4*)&vps[r][c * 4] = *(const float4*)(vp + ((size_t)b * SS + s0 + r) * D2 + c * 4);
    }
    __syncthreads();
    for (int ssi = 0; ssi < ns; ++ssi) {
      float4 v4 = *(const float4*)&vps[ssi][d4];
      #pragma unroll
      for (int j = 0; j < 4; ++j) {
        float p = L[tg * 4 + j][s0 + ssi];
        acc4[j].x = fmaf(p, v4.x, acc4[j].x);
        acc4[j].y = fmaf(p, v4.y, acc4[j].y);
        acc4[j].z = fmaf(p, v4.z, acc4[j].z);
        acc4[j].w = fmaf(p, v4.w, acc4[j].w);
      }
    }
  }
  float* ctg = ws + OFF_CT + ((size_t)b * SS + t0) * D2;
  #pragma unroll
  for (int j = 0; j < 4; ++j) {
    int t = tg * 4 + j;
    if (t < nt) {
      float is = inv_sum[t];
      float4 o;
      o.x = acc4[j].x * is; o.y = acc4[j].y * is;
      o.z = acc4[j].z * is; o.w = acc4[j].w * is;
      *(float4*)(ctg + (size_t)t * D2 + d4) = o;
    }
  }
}

// ---------------- K3: vpc=[vp,ct]; gt=sigmoid(vpc@Wg^T); xin=gt*vpc; gi=xin@Wih^T+b_ih ----------------
// grid: (S/32, B). 32 rows/block.
__global__ __launch_bounds__(256) void k3_gates(const float* __restrict__ vp,
                                                const int* __restrict__ lens,
                                                const float* __restrict__ bih,
                                                float* __restrict__ ws) {
  int b = blockIdx.y;
  int len = lens[b];
  int t0 = blockIdx.x * 32;
  if (t0 >= len) return;
  int nr = min(32, len - t0);

  __shared__ float vpc[32][D4];
  __shared__ float xin[32][D4];
  int tid = threadIdx.x;
  const float* ct = ws + OFF_CT;

  for (int idx = tid; idx < 32 * 128; idx += 256) {
    int r = idx >> 7, c4 = (idx & 127) * 4;
    float4 v;
    if (c4 < D2) v = *(const float4*)(vp + ((size_t)b * SS + t0 + r) * D2 + c4);
    else         v = *(const float4*)(ct + ((size_t)b * SS + t0 + r) * D2 + (c4 - D2));
    *(float4*)&vpc[r][c4] = v;
  }
  __syncthreads();

  // gt phase: thread tile 8 rows x 8 cols
  {
    int j0 = (tid & 63) * 8;
    int rb = (tid >> 6) * 8;
    float acc[8][8] = {};
    const float* wtg = ws + OFF_WTG;
    for (int k = 0; k < D4; ++k) {
      float w[8];
      *(float4*)(w)     = *(const float4*)(wtg + (size_t)k * D4 + j0);
      *(float4*)(w + 4) = *(const float4*)(wtg + (size_t)k * D4 + j0 + 4);
      #pragma unroll
      for (int r = 0; r < 8; ++r) {
        float v = vpc[rb + r][k];
        #pragma unroll
        for (int j = 0; j < 8; ++j) acc[r][j] = fmaf(v, w[j], acc[r][j]);
      }
    }
    #pragma unroll
    for (int r = 0; r < 8; ++r) {
      float4 vA = *(float4*)&vpc[rb + r][j0];
      float4 vB = *(float4*)&vpc[rb + r][j0 + 4];
      float4 oA, oB;
      oA.x = sigm(acc[r][0]) * vA.x; oA.y = sigm(acc[r][1]) * vA.y;
      oA.z = sigm(acc[r][2]) * vA.z; oA.w = sigm(acc[r][3]) * vA.w;
      oB.x = sigm(acc[r][4]) * vB.x; oB.y = sigm(acc[r][5]) * vB.y;
      oB.z = sigm(acc[r][6]) * vB.z; oB.w = sigm(acc[r][7]) * vB.w;
      *(float4*)&xin[rb + r][j0]     = oA;
      *(float4*)&xin[rb + r][j0 + 4] = oB;
    }
  }
  __syncthreads();

  // gi phase: thread owns col jj, jj+128, jj+256 for 16 rows
  {
    int jj = tid & 127;
    int rb2 = (tid >> 7) * 16;
    float a0[16] = {}, a1[16] = {}, a2[16] = {};
    const float* wtih = ws + OFF_WTIH;
    for (int k = 0; k < D4; ++k) {
      float w0 = wtih[(size_t)k * D3 + jj];
      float w1 = wtih[(size_t)k * D3 + jj + 128];
      float w2 = wtih[(size_t)k * D3 + jj + 256];
      #pragma unroll
      for (int r = 0; r < 16; ++r) {
        float v = xin[rb2 + r][k];
        a0[r] = fmaf(v, w0, a0[r]);
        a1[r] = fmaf(v, w1, a1[r]);
        a2[r] = fmaf(v, w2, a2[r]);
      }
    }
    float bi0 = bih[jj], bi1 = bih[jj + 128], bi2 = bih[jj + 256];
    float* gig = ws + OFF_GI + ((size_t)b * SS + t0) * D3;
    #pragma unroll
    for (int r = 0; r < 16; ++r) {
      int rr = rb2 + r;
      if (rr < nr) {
        gig[(size_t)rr * D3 + jj]       = a0[r] + bi0;
        gig[(size_t)rr * D3 + jj + 128] = a1[r] + bi1;
        gig[(size_t)rr * D3 + jj + 256] = a2[r] + bi2;
      }
    }
  }
}

// ---------------- K4: GRU scan, one block per (dir, b) sequence ----------------
__global__ __launch_bounds__(256) void k4_scan(const float* __restrict__ whh,
                                               const float* __restrict__ bhh,
                                               const int* __restrict__ lens,
                                               const float* __restrict__ ws,
                                               float* __restrict__ out) {
  int bid = blockIdx.x;
  int b = bid & 31, dir = bid >> 5;
  int len = lens[b];
  int tid = threadIdx.x;
  const float* gi = ws + OFF_GI + (size_t)b * SS * D3;

  int row0 = tid;
  int row1 = tid + 256;  // valid only if tid < 128
  h2_t w0[64], w1[64];
  float bh0 = bhh[row0];
  float bh1 = 0.0f;
  #pragma unroll
  for (int k = 0; k < 64; ++k) {
    float a = whh[(size_t)row0 * HH + 2 * k];
    float c = whh[(size_t)row0 * HH + 2 * k + 1];
    w0[k] = h2_t{(_Float16)a, (_Float16)c};
  }
  if (tid < 128) {
    bh1 = bhh[row1];
    #pragma unroll
    for (int k = 0; k < 64; ++k) {
      float a = whh[(size_t)row1 * HH + 2 * k];
      float c = whh[(size_t)row1 * HH + 2 * k + 1];
      w1[k] = h2_t{(_Float16)a, (_Float16)c};
    }
  } else {
    #pragma unroll
    for (int k = 0; k < 64; ++k) w1[k] = h2_t{(_Float16)0.0f, (_Float16)0.0f};
  }

  __shared__ __align__(16) _Float16 hbuf[128];
  __shared__ float gsum[D3];
  if (tid < 128) hbuf[tid] = (_Float16)0.0f;
  float h_own = 0.0f;
  __syncthreads();

  float* outb = out + (size_t)b * SS * D2 + dir * HH;
  for (int t = 0; t < len; ++t) {
    int tg = dir ? (len - 1 - t) : t;
    const float* gr = gi + (size_t)tg * D3;
    float gv0 = 0.0f, gv1 = 0.0f, gv2 = 0.0f;
    if (tid < 128) {
      gv0 = gr[tid];
      gv1 = gr[tid + 128];
      gv2 = gr[tid + 256];
    }
    float acc0 = bh0, acc1 = bh1;
    const h2_t* hb = (const h2_t*)hbuf;
    #pragma unroll
    for (int k = 0; k < 64; ++k) {
      h2_t hv = hb[k];
      acc0 = __builtin_amdgcn_fdot2(hv, w0[k], acc0, false);
      acc1 = __builtin_amdgcn_fdot2(hv, w1[k], acc1, false);
    }
    gsum[row0] = acc0;
    if (tid < 128) gsum[row1] = acc1;
    __syncthreads();
    if (tid < 128) {
      float r = sigm(gv0 + gsum[tid]);
      float z = sigm(gv1 + gsum[tid + 128]);
      float n = fast_tanh(fmaf(r, gsum[tid + 256], gv2));
      float hn = (1.0f - z) * n + z * h_own;
      h_own = hn;
      outb[(size_t)t * D2 + tid] = hn;
      hbuf[tid] = (_Float16)hn;
    }
    __syncthreads();
  }
}

extern "C" void kernel_launch(void* const* d_in, const int* in_sizes, int n_in,
                              void* d_out, int out_size, void* d_ws, size_t ws_size,
                              hipStream_t stream) {
  const float* vp   = (const float*)d_in[0];
  const int*   lens = (const int*)d_in[1];
  const float* Wvp  = (const float*)d_in[2];
  const float* Wvpt = (const float*)d_in[3];
  const float* wvt  = (const float*)d_in[4];
  const float* Wg   = (const float*)d_in[5];
  const float* Wih  = (const float*)d_in[6];
  const float* Whh  = (const float*)d_in[7];
  const float* bih  = (const float*)d_in[8];
  const float* bhh  = (const float*)d_in[9];
  float* out = (float*)d_out;
  float* ws  = (float*)d_ws;

  hipMemsetAsync(d_out, 0, (size_t)out_size * sizeof(float), stream);

  k0_transpose<<<2048, 256, 0, stream>>>(Wg, Wih, Wvp, Wvpt, ws);
  k1_keyq<<<dim3(BB * SS / 64, 2), 256, 0, stream>>>(vp, ws);
  k2_attn<<<dim3(SS / 16, BB), 256, 0, stream>>>(vp, lens, wvt, ws);
  k3_gates<<<dim3(SS / 32, BB), 256, 0, stream>>>(vp, lens, bih, ws);
  k4_scan<<<64, 256, 0, stream>>>(Whh, bhh, lens, ws, out);
}

// Round 2
// 819.643 us; speedup vs baseline: 1.4740x; 1.4740x over previous
//
#include <hip/hip_runtime.h>
#include <hip/hip_fp16.h>

#define BB 32
#define SS 512
#define HH 128
#define D2 256
#define D3 384
#define D4 512

// ws layout (float offsets)
#define OFF_TK  0
#define OFF_TQ  (OFF_TK + BB*SS*HH)     // tanh(keyp) [B][S][H] f32
#define OFF_CT  (OFF_TQ + BB*SS*HH)     // context   [B][S][2H] f32
#define OFF_GI  (OFF_CT + BB*SS*D2)     // gi        [B][S][3H] f32
#define OFF_F16 (OFF_GI + BB*SS*D3)     // f16 weight region below (element offsets)
#define F16_WG  0                       // Wg  f16 [512][512] row-major (as given)
#define F16_WIH (F16_WG + D4*D4)        // Wih f16 [384][512]
#define F16_W2  (F16_WIH + D3*D4)       // [WvP;WvPt] f16 [256][256]

typedef _Float16 f16x8 __attribute__((ext_vector_type(8)));
typedef _Float16 f16x4 __attribute__((ext_vector_type(4)));
typedef float    f32x4 __attribute__((ext_vector_type(4)));
typedef _Float16 h2_t  __attribute__((ext_vector_type(2)));

__device__ __forceinline__ float fast_tanh(float x) {
  float ax = fabsf(x);
  float e  = __expf(-2.0f * ax);
  float t  = __fdividef(1.0f - e, 1.0f + e);
  return x < 0.0f ? -t : t;
}
__device__ __forceinline__ float sigm(float x) {
  return __fdividef(1.0f, 1.0f + __expf(-x));
}

// ---------------- K0: convert weights to f16 in ws ----------------
__global__ __launch_bounds__(256) void k0_prep(
    const float* __restrict__ Wg, const float* __restrict__ Wih,
    const float* __restrict__ Wvp, const float* __restrict__ Wvpt,
    float* __restrict__ ws) {
  int i = blockIdx.x * 256 + threadIdx.x;
  _Float16* f16b = (_Float16*)(ws + OFF_F16);
  if (i < D4 * D4) {
    f16b[F16_WG + i] = (_Float16)Wg[i];
  } else if (i < D4 * D4 + D3 * D4) {
    int j = i - D4 * D4;
    f16b[F16_WIH + j] = (_Float16)Wih[j];
  } else {
    int j = i - D4 * D4 - D3 * D4;   // < 65536
    f16b[F16_W2 + j] = (_Float16)(j < HH * D2 ? Wvp[j] : Wvpt[j - HH * D2]);
  }
}

// ---------------- K1: [tk|tq]^T = [WvP;WvPt]_f16 . vp^T via MFMA ----------------
// 64 rows/block, 256 blocks. Wave w owns cols [w*64, w*64+64).
__global__ __launch_bounds__(256, 2) void k1_keyq(const float* __restrict__ vp,
                                                  float* __restrict__ ws) {
  __shared__ __align__(16) _Float16 vpH[64 * 256];
  int tid = threadIdx.x;
  int rows0 = blockIdx.x * 64;

  #pragma unroll
  for (int i = 0; i < 8; ++i) {
    int u = tid + i * 256;
    int r = u >> 5, c8 = u & 31;
    const float* src = vp + (size_t)(rows0 + r) * D2 + c8 * 8;
    float4 a = *(const float4*)src;
    float4 b = *(const float4*)(src + 4);
    f16x8 h;
    h[0]=(_Float16)a.x; h[1]=(_Float16)a.y; h[2]=(_Float16)a.z; h[3]=(_Float16)a.w;
    h[4]=(_Float16)b.x; h[5]=(_Float16)b.y; h[6]=(_Float16)b.z; h[7]=(_Float16)b.w;
    *(f16x8*)(&vpH[r * 256 + (c8 ^ (r & 7)) * 8]) = h;
  }
  __syncthreads();

  const _Float16* W2 = (const _Float16*)(ws + OFF_F16) + F16_W2;
  int w = tid >> 6, l = tid & 63;
  int lr = l & 15, lk = (l >> 4) * 8;

  f32x4 acc[4][4];
  #pragma unroll
  for (int m = 0; m < 4; ++m)
    #pragma unroll
    for (int n = 0; n < 4; ++n) acc[m][n] = (f32x4){0.f, 0.f, 0.f, 0.f};

  for (int kc = 0; kc < 8; ++kc) {
    int k = kc * 32 + lk;
    f16x8 bf[4];
    #pragma unroll
    for (int n = 0; n < 4; ++n) {
      int r = n * 16 + lr;
      bf[n] = *(const f16x8*)(&vpH[r * 256 + (((k >> 3) ^ (r & 7))) * 8]);
    }
    #pragma unroll
    for (int m = 0; m < 4; ++m) {
      int c = w * 64 + m * 16 + lr;
      f16x8 af = *(const f16x8*)(W2 + (size_t)c * 256 + k);
      #pragma unroll
      for (int n = 0; n < 4; ++n)
        acc[m][n] = __builtin_amdgcn_mfma_f32_16x16x32_f16(af, bf[n], acc[m][n], 0, 0, 0);
    }
  }

  float* tkp = ws + OFF_TK;
  float* tqp = ws + OFF_TQ;
  #pragma unroll
  for (int m = 0; m < 4; ++m) {
    int c0 = w * 64 + m * 16 + (l >> 4) * 4;
    #pragma unroll
    for (int n = 0; n < 4; ++n) {
      int row = rows0 + n * 16 + lr;
      float4 o;
      o.x = fast_tanh(acc[m][n][0]);
      o.y = fast_tanh(acc[m][n][1]);
      o.z = fast_tanh(acc[m][n][2]);
      o.w = fast_tanh(acc[m][n][3]);
      float* dst = (c0 < HH) ? (tkp + (size_t)row * HH + c0)
                             : (tqp + (size_t)row * HH + (c0 - HH));
      *(float4*)dst = o;
    }
  }
}

// ---------------- K2: logits (rational tanh) + softmax + ct ----------------
__global__ __launch_bounds__(256) void k2_attn(const float* __restrict__ vp,
                                               const int* __restrict__ lens,
                                               const float* __restrict__ wvt,
                                               float* __restrict__ ws) {
  int b = blockIdx.y;
  int len = lens[b];
  int t0 = blockIdx.x * 16;
  if (t0 >= len) return;
  int nt = min(16, len - t0);

  __shared__ float L[16][SS];
  __shared__ float tqt[16][HH];
  __shared__ float vps[32][D2];
  __shared__ float inv_sum[16];

  int tid = threadIdx.x;
  const float* tk = ws + OFF_TK + (size_t)b * SS * HH;
  const float* tq = ws + OFF_TQ + (size_t)b * SS * HH;

  for (int idx = tid; idx < 16 * HH; idx += 256) {
    int i = idx >> 7, h = idx & 127;
    tqt[i][h] = tq[(size_t)(t0 + i) * HH + h];
  }
  __syncthreads();

  for (int sc = 0; sc < 2; ++sc) {
    int s = tid + sc * 256;
    if (s < len) {
      float acc[16] = {};
      const float* tkr = tk + (size_t)s * HH;
      for (int h4 = 0; h4 < 32; ++h4) {
        const float4 k4 = *(const float4*)(tkr + h4 * 4);
        const float4 w4 = *(const float4*)(wvt + h4 * 4);
        #pragma unroll
        for (int t = 0; t < 16; ++t) {
          const float4 q4 = *(const float4*)(&tqt[t][h4 * 4]);
          float n0 = k4.x + q4.x, n1 = k4.y + q4.y, n2 = k4.z + q4.z, n3 = k4.w + q4.w;
          float e0 = fmaf(k4.x, q4.x, 1.0f), e1 = fmaf(k4.y, q4.y, 1.0f);
          float e2 = fmaf(k4.z, q4.z, 1.0f), e3 = fmaf(k4.w, q4.w, 1.0f);
          float m01 = e0 * e1, m23 = e2 * e3;
          float rall = __fdividef(1.0f, m01 * m23);
          float r01 = rall * m23, r23 = rall * m01;
          float i0 = r01 * e1, i1 = r01 * e0, i2 = r23 * e3, i3 = r23 * e2;
          float a = acc[t];
          a = fmaf(w4.x, n0 * i0, a);
          a = fmaf(w4.y, n1 * i1, a);
          a = fmaf(w4.z, n2 * i2, a);
          a = fmaf(w4.w, n3 * i3, a);
          acc[t] = a;
        }
      }
      #pragma unroll
      for (int t = 0; t < 16; ++t) L[t][s] = acc[t];
    }
  }
  __syncthreads();

  {
    int w = tid >> 6, lane = tid & 63;
    for (int ii = 0; ii < 4; ++ii) {
      int i = w + ii * 4;
      if (i < nt) {
        float m = -1e30f;
        for (int s = lane; s < len; s += 64) m = fmaxf(m, L[i][s]);
        #pragma unroll
        for (int off = 32; off > 0; off >>= 1) m = fmaxf(m, __shfl_xor(m, off));
        float sm = 0.0f;
        for (int s = lane; s < len; s += 64) {
          float e = __expf(L[i][s] - m);
          L[i][s] = e;
          sm += e;
        }
        #pragma unroll
        for (int off = 32; off > 0; off >>= 1) sm += __shfl_xor(sm, off);
        if (lane == 0) inv_sum[i] = __fdividef(1.0f, sm);
      }
    }
  }
  __syncthreads();

  int d4 = (tid & 63) * 4;
  int tg = tid >> 6;
  float4 acc4[4] = {};
  for (int s0 = 0; s0 < len; s0 += 32) {
    int ns = min(32, len - s0);
    __syncthreads();
    for (int idx = tid; idx < 32 * 64; idx += 256) {
      int r = idx >> 6, c = idx & 63;
      if (r < ns)
        *(float4*)&vps[r][c * 4] = *(const float4*)(vp + ((size_t)b * SS + s0 + r) * D2 + c * 4);
    }
    __syncthreads();
    for (int ssi = 0; ssi < ns; ++ssi) {
      float4 v4 = *(const float4*)&vps[ssi][d4];
      #pragma unroll
      for (int j = 0; j < 4; ++j) {
        float p = L[tg * 4 + j][s0 + ssi];
        acc4[j].x = fmaf(p, v4.x, acc4[j].x);
        acc4[j].y = fmaf(p, v4.y, acc4[j].y);
        acc4[j].z = fmaf(p, v4.z, acc4[j].z);
        acc4[j].w = fmaf(p, v4.w, acc4[j].w);
      }
    }
  }
  float* ctg = ws + OFF_CT + ((size_t)b * SS + t0) * D2;
  #pragma unroll
  for (int j = 0; j < 4; ++j) {
    int t = tg * 4 + j;
    if (t < nt) {
      float is = inv_sum[t];
      float4 o;
      o.x = acc4[j].x * is; o.y = acc4[j].y * is;
      o.z = acc4[j].z * is; o.w = acc4[j].w * is;
      *(float4*)(ctg + (size_t)t * D2 + d4) = o;
    }
  }
}

// ---------------- K3: gt' = Wg.vpc^T -> xin (in-place LDS) -> gi' = Wih.xin^T ----------------
// 32 rows/block; grid (16, B). Wave w: gt cols [w*128,+128), gi cols [w*96,+96).
__global__ __launch_bounds__(256, 2) void k3_gates(const float* __restrict__ vp,
                                                   const int* __restrict__ lens,
                                                   const float* __restrict__ bih,
                                                   float* __restrict__ ws) {
  int b = blockIdx.y;
  int len = lens[b];
  int t0 = blockIdx.x * 32;
  if (t0 >= len) return;

  __shared__ __align__(16) _Float16 vpcH[32 * 512];
  int tid = threadIdx.x;
  const float* ct = ws + OFF_CT;

  #pragma unroll
  for (int i = 0; i < 8; ++i) {
    int u = tid + i * 256;
    int r = u >> 6, c8 = u & 63;
    int c = c8 * 8;
    const float* src = (c < D2) ? (vp + ((size_t)b * SS + t0 + r) * D2 + c)
                                : (ct + ((size_t)b * SS + t0 + r) * D2 + (c - D2));
    float4 a = *(const float4*)src;
    float4 bb = *(const float4*)(src + 4);
    f16x8 h;
    h[0]=(_Float16)a.x;  h[1]=(_Float16)a.y;  h[2]=(_Float16)a.z;  h[3]=(_Float16)a.w;
    h[4]=(_Float16)bb.x; h[5]=(_Float16)bb.y; h[6]=(_Float16)bb.z; h[7]=(_Float16)bb.w;
    *(f16x8*)(&vpcH[r * 512 + (c8 ^ (r & 7)) * 8]) = h;
  }
  __syncthreads();

  const _Float16* WgH  = (const _Float16*)(ws + OFF_F16) + F16_WG;
  const _Float16* WihH = (const _Float16*)(ws + OFF_F16) + F16_WIH;
  int w = tid >> 6, l = tid & 63;
  int lr = l & 15, lk = (l >> 4) * 8;

  // ---- gt' phase ----
  f32x4 acc[8][2];
  #pragma unroll
  for (int m = 0; m < 8; ++m) { acc[m][0] = (f32x4){0.f,0.f,0.f,0.f}; acc[m][1] = (f32x4){0.f,0.f,0.f,0.f}; }

  for (int kc = 0; kc < 16; ++kc) {
    int k = kc * 32 + lk;
    f16x8 bf[2];
    #pragma unroll
    for (int n = 0; n < 2; ++n) {
      int r = n * 16 + lr;
      bf[n] = *(const f16x8*)(&vpcH[r * 512 + (((k >> 3) ^ (r & 7))) * 8]);
    }
    #pragma unroll
    for (int m = 0; m < 8; ++m) {
      int c = w * 128 + m * 16 + lr;
      f16x8 af = *(const f16x8*)(WgH + (size_t)c * 512 + k);
      acc[m][0] = __builtin_amdgcn_mfma_f32_16x16x32_f16(af, bf[0], acc[m][0], 0, 0, 0);
      acc[m][1] = __builtin_amdgcn_mfma_f32_16x16x32_f16(af, bf[1], acc[m][1], 0, 0, 0);
    }
  }

  // epilogue: xin = sigmoid(gt)*vpc, quads of contiguous c at fixed r
  f16x4 xq[8][2];
  #pragma unroll
  for (int m = 0; m < 8; ++m) {
    int c0 = w * 128 + m * 16 + (l >> 4) * 4;
    #pragma unroll
    for (int n = 0; n < 2; ++n) {
      int r = n * 16 + lr;
      int ea = r * 512 + (((c0 >> 3) ^ (r & 7))) * 8 + (c0 & 7);
      f16x4 vq = *(const f16x4*)(&vpcH[ea]);
      f16x4 xo;
      #pragma unroll
      for (int j = 0; j < 4; ++j)
        xo[j] = (_Float16)(sigm(acc[m][n][j]) * (float)vq[j]);
      xq[m][n] = xo;
    }
  }
  __syncthreads();
  #pragma unroll
  for (int m = 0; m < 8; ++m) {
    int c0 = w * 128 + m * 16 + (l >> 4) * 4;
    #pragma unroll
    for (int n = 0; n < 2; ++n) {
      int r = n * 16 + lr;
      int ea = r * 512 + (((c0 >> 3) ^ (r & 7))) * 8 + (c0 & 7);
      *(f16x4*)(&vpcH[ea]) = xq[m][n];
    }
  }
  __syncthreads();

  // ---- gi' phase (vpcH now holds xin) ----
  f32x4 gacc[6][2];
  #pragma unroll
  for (int m = 0; m < 6; ++m) { gacc[m][0] = (f32x4){0.f,0.f,0.f,0.f}; gacc[m][1] = (f32x4){0.f,0.f,0.f,0.f}; }

  for (int kc = 0; kc < 16; ++kc) {
    int k = kc * 32 + lk;
    f16x8 bf[2];
    #pragma unroll
    for (int n = 0; n < 2; ++n) {
      int r = n * 16 + lr;
      bf[n] = *(const f16x8*)(&vpcH[r * 512 + (((k >> 3) ^ (r & 7))) * 8]);
    }
    #pragma unroll
    for (int m = 0; m < 6; ++m) {
      int c = w * 96 + m * 16 + lr;
      f16x8 af = *(const f16x8*)(WihH + (size_t)c * 512 + k);
      gacc[m][0] = __builtin_amdgcn_mfma_f32_16x16x32_f16(af, bf[0], gacc[m][0], 0, 0, 0);
      gacc[m][1] = __builtin_amdgcn_mfma_f32_16x16x32_f16(af, bf[1], gacc[m][1], 0, 0, 0);
    }
  }

  float* gig = ws + OFF_GI;
  #pragma unroll
  for (int m = 0; m < 6; ++m) {
    int c0 = w * 96 + m * 16 + (l >> 4) * 4;
    float4 bq = *(const float4*)(bih + c0);
    #pragma unroll
    for (int n = 0; n < 2; ++n) {
      int r = n * 16 + lr;
      float4 o;
      o.x = gacc[m][n][0] + bq.x;
      o.y = gacc[m][n][1] + bq.y;
      o.z = gacc[m][n][2] + bq.z;
      o.w = gacc[m][n][3] + bq.w;
      *(float4*)(gig + ((size_t)b * SS + t0 + r) * D3 + c0) = o;
    }
  }
}

// ---------------- K4: GRU scan, one block per (dir, b) sequence ----------------
__global__ __launch_bounds__(256) void k4_scan(const float* __restrict__ whh,
                                               const float* __restrict__ bhh,
                                               const int* __restrict__ lens,
                                               const float* __restrict__ ws,
                                               float* __restrict__ out) {
  int bid = blockIdx.x;
  int b = bid & 31, dir = bid >> 5;
  int len = lens[b];
  int tid = threadIdx.x;
  const float* gi = ws + OFF_GI + (size_t)b * SS * D3;

  int row0 = tid;
  int row1 = tid + 256;
  h2_t w0[64], w1[64];
  float bh0 = bhh[row0];
  float bh1 = 0.0f;
  #pragma unroll
  for (int k = 0; k < 64; ++k) {
    float a = whh[(size_t)row0 * HH + 2 * k];
    float c = whh[(size_t)row0 * HH + 2 * k + 1];
    w0[k] = h2_t{(_Float16)a, (_Float16)c};
  }
  if (tid < 128) {
    bh1 = bhh[row1];
    #pragma unroll
    for (int k = 0; k < 64; ++k) {
      float a = whh[(size_t)row1 * HH + 2 * k];
      float c = whh[(size_t)row1 * HH + 2 * k + 1];
      w1[k] = h2_t{(_Float16)a, (_Float16)c};
    }
  } else {
    #pragma unroll
    for (int k = 0; k < 64; ++k) w1[k] = h2_t{(_Float16)0.0f, (_Float16)0.0f};
  }

  __shared__ __align__(16) _Float16 hbuf[128];
  __shared__ float gsum[D3];
  if (tid < 128) hbuf[tid] = (_Float16)0.0f;
  float h_own = 0.0f;
  __syncthreads();

  float* outb = out + (size_t)b * SS * D2 + dir * HH;
  for (int t = 0; t < len; ++t) {
    int tg = dir ? (len - 1 - t) : t;
    const float* gr = gi + (size_t)tg * D3;
    float gv0 = 0.0f, gv1 = 0.0f, gv2 = 0.0f;
    if (tid < 128) {
      gv0 = gr[tid];
      gv1 = gr[tid + 128];
      gv2 = gr[tid + 256];
    }
    float acc0 = bh0, acc1 = bh1;
    const h2_t* hb = (const h2_t*)hbuf;
    #pragma unroll
    for (int k = 0; k < 64; ++k) {
      h2_t hv = hb[k];
      acc0 = __builtin_amdgcn_fdot2(hv, w0[k], acc0, false);
      acc1 = __builtin_amdgcn_fdot2(hv, w1[k], acc1, false);
    }
    gsum[row0] = acc0;
    if (tid < 128) gsum[row1] = acc1;
    __syncthreads();
    if (tid < 128) {
      float r = sigm(gv0 + gsum[tid]);
      float z = sigm(gv1 + gsum[tid + 128]);
      float n = fast_tanh(fmaf(r, gsum[tid + 256], gv2));
      float hn = (1.0f - z) * n + z * h_own;
      h_own = hn;
      outb[(size_t)t * D2 + tid] = hn;
      hbuf[tid] = (_Float16)hn;
    }
    __syncthreads();
  }
}

extern "C" void kernel_launch(void* const* d_in, const int* in_sizes, int n_in,
                              void* d_out, int out_size, void* d_ws, size_t ws_size,
                              hipStream_t stream) {
  const float* vp   = (const float*)d_in[0];
  const int*   lens = (const int*)d_in[1];
  const float* Wvp  = (const float*)d_in[2];
  const float* Wvpt = (const float*)d_in[3];
  const float* wvt  = (const float*)d_in[4];
  const float* Wg   = (const float*)d_in[5];
  const float* Wih  = (const float*)d_in[6];
  const float* Whh  = (const float*)d_in[7];
  const float* bih  = (const float*)d_in[8];
  const float* bhh  = (const float*)d_in[9];
  float* out = (float*)d_out;
  float* ws  = (float*)d_ws;

  hipMemsetAsync(d_out, 0, (size_t)out_size * sizeof(float), stream);

  k0_prep<<<2048, 256, 0, stream>>>(Wg, Wih, Wvp, Wvpt, ws);
  k1_keyq<<<BB * SS / 64, 256, 0, stream>>>(vp, ws);
  k2_attn<<<dim3(SS / 16, BB), 256, 0, stream>>>(vp, lens, wvt, ws);
  k3_gates<<<dim3(SS / 32, BB), 256, 0, stream>>>(vp, lens, bih, ws);
  k4_scan<<<64, 256, 0, stream>>>(Whh, bhh, lens, ws, out);
}

// Round 3
// 751.247 us; speedup vs baseline: 1.6082x; 1.0910x over previous
//
#include <hip/hip_runtime.h>
#include <hip/hip_fp16.h>

#define BB 32
#define SS 512
#define HH 128
#define D2 256
#define D3 384
#define D4 512

// ws layout (float offsets)
#define OFF_TK  0
#define OFF_TQ  (OFF_TK + BB*SS*HH)     // tanh(keyp) [B][S][H] f32
#define OFF_CT  (OFF_TQ + BB*SS*HH)     // context   [B][S][2H] f32
#define OFF_GI  (OFF_CT + BB*SS*D2)     // gi        [B][S][3H] f32
#define OFF_F16 (OFF_GI + BB*SS*D3)     // f16 weight region below (element offsets)
#define F16_WG  0                       // Wg  f16 [512][512] row-major (as given)
#define F16_WIH (F16_WG + D4*D4)        // Wih f16 [384][512]
#define F16_W2  (F16_WIH + D3*D4)       // [WvP;WvPt] f16 [256][256]

typedef _Float16 f16x8 __attribute__((ext_vector_type(8)));
typedef _Float16 f16x4 __attribute__((ext_vector_type(4)));
typedef float    f32x4 __attribute__((ext_vector_type(4)));
typedef _Float16 h2_t  __attribute__((ext_vector_type(2)));

__device__ __forceinline__ float fast_tanh(float x) {
  float ax = fabsf(x);
  float e  = __expf(-2.0f * ax);
  float t  = __fdividef(1.0f - e, 1.0f + e);
  return x < 0.0f ? -t : t;
}
__device__ __forceinline__ float sigm(float x) {
  return __fdividef(1.0f, 1.0f + __expf(-x));
}

// ---------------- K0: convert weights to f16 in ws ----------------
__global__ __launch_bounds__(256) void k0_prep(
    const float* __restrict__ Wg, const float* __restrict__ Wih,
    const float* __restrict__ Wvp, const float* __restrict__ Wvpt,
    float* __restrict__ ws) {
  int i = blockIdx.x * 256 + threadIdx.x;
  _Float16* f16b = (_Float16*)(ws + OFF_F16);
  if (i < D4 * D4) {
    f16b[F16_WG + i] = (_Float16)Wg[i];
  } else if (i < D4 * D4 + D3 * D4) {
    int j = i - D4 * D4;
    f16b[F16_WIH + j] = (_Float16)Wih[j];
  } else {
    int j = i - D4 * D4 - D3 * D4;   // < 65536
    f16b[F16_W2 + j] = (_Float16)(j < HH * D2 ? Wvp[j] : Wvpt[j - HH * D2]);
  }
}

// ---------------- K1: [tk|tq]^T = [WvP;WvPt]_f16 . vp^T via MFMA ----------------
__global__ __launch_bounds__(256, 2) void k1_keyq(const float* __restrict__ vp,
                                                  float* __restrict__ ws) {
  __shared__ __align__(16) _Float16 vpH[64 * 256];
  int tid = threadIdx.x;
  int rows0 = blockIdx.x * 64;

  #pragma unroll
  for (int i = 0; i < 8; ++i) {
    int u = tid + i * 256;
    int r = u >> 5, c8 = u & 31;
    const float* src = vp + (size_t)(rows0 + r) * D2 + c8 * 8;
    float4 a = *(const float4*)src;
    float4 b = *(const float4*)(src + 4);
    f16x8 h;
    h[0]=(_Float16)a.x; h[1]=(_Float16)a.y; h[2]=(_Float16)a.z; h[3]=(_Float16)a.w;
    h[4]=(_Float16)b.x; h[5]=(_Float16)b.y; h[6]=(_Float16)b.z; h[7]=(_Float16)b.w;
    *(f16x8*)(&vpH[r * 256 + (c8 ^ (r & 7)) * 8]) = h;
  }
  __syncthreads();

  const _Float16* W2 = (const _Float16*)(ws + OFF_F16) + F16_W2;
  int w = tid >> 6, l = tid & 63;
  int lr = l & 15, lk = (l >> 4) * 8;

  f32x4 acc[4][4];
  #pragma unroll
  for (int m = 0; m < 4; ++m)
    #pragma unroll
    for (int n = 0; n < 4; ++n) acc[m][n] = (f32x4){0.f, 0.f, 0.f, 0.f};

  for (int kc = 0; kc < 8; ++kc) {
    int k = kc * 32 + lk;
    f16x8 bf[4];
    #pragma unroll
    for (int n = 0; n < 4; ++n) {
      int r = n * 16 + lr;
      bf[n] = *(const f16x8*)(&vpH[r * 256 + (((k >> 3) ^ (r & 7))) * 8]);
    }
    #pragma unroll
    for (int m = 0; m < 4; ++m) {
      int c = w * 64 + m * 16 + lr;
      f16x8 af = *(const f16x8*)(W2 + (size_t)c * 256 + k);
      #pragma unroll
      for (int n = 0; n < 4; ++n)
        acc[m][n] = __builtin_amdgcn_mfma_f32_16x16x32_f16(af, bf[n], acc[m][n], 0, 0, 0);
    }
  }

  float* tkp = ws + OFF_TK;
  float* tqp = ws + OFF_TQ;
  #pragma unroll
  for (int m = 0; m < 4; ++m) {
    int c0 = w * 64 + m * 16 + (l >> 4) * 4;
    #pragma unroll
    for (int n = 0; n < 4; ++n) {
      int row = rows0 + n * 16 + lr;
      float4 o;
      o.x = fast_tanh(acc[m][n][0]);
      o.y = fast_tanh(acc[m][n][1]);
      o.z = fast_tanh(acc[m][n][2]);
      o.w = fast_tanh(acc[m][n][3]);
      float* dst = (c0 < HH) ? (tkp + (size_t)row * HH + c0)
                             : (tqp + (size_t)row * HH + (c0 - HH));
      *(float4*)dst = o;
    }
  }
}

// ---------------- K2: logits (rational tanh) + softmax + ct ----------------
__global__ __launch_bounds__(256) void k2_attn(const float* __restrict__ vp,
                                               const int* __restrict__ lens,
                                               const float* __restrict__ wvt,
                                               float* __restrict__ ws) {
  int b = blockIdx.y;
  int len = lens[b];
  int t0 = blockIdx.x * 16;
  if (t0 >= len) return;
  int nt = min(16, len - t0);

  __shared__ float L[16][SS];
  __shared__ float tqt[16][HH];
  __shared__ float vps[32][D2];
  __shared__ float inv_sum[16];

  int tid = threadIdx.x;
  const float* tk = ws + OFF_TK + (size_t)b * SS * HH;
  const float* tq = ws + OFF_TQ + (size_t)b * SS * HH;

  for (int idx = tid; idx < 16 * HH; idx += 256) {
    int i = idx >> 7, h = idx & 127;
    tqt[i][h] = tq[(size_t)(t0 + i) * HH + h];
  }
  __syncthreads();

  for (int sc = 0; sc < 2; ++sc) {
    int s = tid + sc * 256;
    if (s < len) {
      float acc[16] = {};
      const float* tkr = tk + (size_t)s * HH;
      for (int h4 = 0; h4 < 32; ++h4) {
        const float4 k4 = *(const float4*)(tkr + h4 * 4);
        const float4 w4 = *(const float4*)(wvt + h4 * 4);
        #pragma unroll
        for (int t = 0; t < 16; ++t) {
          const float4 q4 = *(const float4*)(&tqt[t][h4 * 4]);
          float n0 = k4.x + q4.x, n1 = k4.y + q4.y, n2 = k4.z + q4.z, n3 = k4.w + q4.w;
          float e0 = fmaf(k4.x, q4.x, 1.0f), e1 = fmaf(k4.y, q4.y, 1.0f);
          float e2 = fmaf(k4.z, q4.z, 1.0f), e3 = fmaf(k4.w, q4.w, 1.0f);
          float m01 = e0 * e1, m23 = e2 * e3;
          float rall = __fdividef(1.0f, m01 * m23);
          float r01 = rall * m23, r23 = rall * m01;
          float i0 = r01 * e1, i1 = r01 * e0, i2 = r23 * e3, i3 = r23 * e2;
          float a = acc[t];
          a = fmaf(w4.x, n0 * i0, a);
          a = fmaf(w4.y, n1 * i1, a);
          a = fmaf(w4.z, n2 * i2, a);
          a = fmaf(w4.w, n3 * i3, a);
          acc[t] = a;
        }
      }
      #pragma unroll
      for (int t = 0; t < 16; ++t) L[t][s] = acc[t];
    }
  }
  __syncthreads();

  {
    int w = tid >> 6, lane = tid & 63;
    for (int ii = 0; ii < 4; ++ii) {
      int i = w + ii * 4;
      if (i < nt) {
        float m = -1e30f;
        for (int s = lane; s < len; s += 64) m = fmaxf(m, L[i][s]);
        #pragma unroll
        for (int off = 32; off > 0; off >>= 1) m = fmaxf(m, __shfl_xor(m, off));
        float sm = 0.0f;
        for (int s = lane; s < len; s += 64) {
          float e = __expf(L[i][s] - m);
          L[i][s] = e;
          sm += e;
        }
        #pragma unroll
        for (int off = 32; off > 0; off >>= 1) sm += __shfl_xor(sm, off);
        if (lane == 0) inv_sum[i] = __fdividef(1.0f, sm);
      }
    }
  }
  __syncthreads();

  int d4 = (tid & 63) * 4;
  int tg = tid >> 6;
  float4 acc4[4] = {};
  for (int s0 = 0; s0 < len; s0 += 32) {
    int ns = min(32, len - s0);
    __syncthreads();
    for (int idx = tid; idx < 32 * 64; idx += 256) {
      int r = idx >> 6, c = idx & 63;
      if (r < ns)
        *(float4*)&vps[r][c * 4] = *(const float4*)(vp + ((size_t)b * SS + s0 + r) * D2 + c * 4);
    }
    __syncthreads();
    for (int ssi = 0; ssi < ns; ++ssi) {
      float4 v4 = *(const float4*)&vps[ssi][d4];
      #pragma unroll
      for (int j = 0; j < 4; ++j) {
        float p = L[tg * 4 + j][s0 + ssi];
        acc4[j].x = fmaf(p, v4.x, acc4[j].x);
        acc4[j].y = fmaf(p, v4.y, acc4[j].y);
        acc4[j].z = fmaf(p, v4.z, acc4[j].z);
        acc4[j].w = fmaf(p, v4.w, acc4[j].w);
      }
    }
  }
  float* ctg = ws + OFF_CT + ((size_t)b * SS + t0) * D2;
  #pragma unroll
  for (int j = 0; j < 4; ++j) {
    int t = tg * 4 + j;
    if (t < nt) {
      float is = inv_sum[t];
      float4 o;
      o.x = acc4[j].x * is; o.y = acc4[j].y * is;
      o.z = acc4[j].z * is; o.w = acc4[j].w * is;
      *(float4*)(ctg + (size_t)t * D2 + d4) = o;
    }
  }
}

// ---------------- K3: gt' = Wg.vpc^T -> xin (in-place LDS) -> gi' = Wih.xin^T ----------------
__global__ __launch_bounds__(256, 2) void k3_gates(const float* __restrict__ vp,
                                                   const int* __restrict__ lens,
                                                   const float* __restrict__ bih,
                                                   float* __restrict__ ws) {
  int b = blockIdx.y;
  int len = lens[b];
  int t0 = blockIdx.x * 32;
  if (t0 >= len) return;

  __shared__ __align__(16) _Float16 vpcH[32 * 512];
  int tid = threadIdx.x;
  const float* ct = ws + OFF_CT;

  #pragma unroll
  for (int i = 0; i < 8; ++i) {
    int u = tid + i * 256;
    int r = u >> 6, c8 = u & 63;
    int c = c8 * 8;
    const float* src = (c < D2) ? (vp + ((size_t)b * SS + t0 + r) * D2 + c)
                                : (ct + ((size_t)b * SS + t0 + r) * D2 + (c - D2));
    float4 a = *(const float4*)src;
    float4 bb = *(const float4*)(src + 4);
    f16x8 h;
    h[0]=(_Float16)a.x;  h[1]=(_Float16)a.y;  h[2]=(_Float16)a.z;  h[3]=(_Float16)a.w;
    h[4]=(_Float16)bb.x; h[5]=(_Float16)bb.y; h[6]=(_Float16)bb.z; h[7]=(_Float16)bb.w;
    *(f16x8*)(&vpcH[r * 512 + (c8 ^ (r & 7)) * 8]) = h;
  }
  __syncthreads();

  const _Float16* WgH  = (const _Float16*)(ws + OFF_F16) + F16_WG;
  const _Float16* WihH = (const _Float16*)(ws + OFF_F16) + F16_WIH;
  int w = tid >> 6, l = tid & 63;
  int lr = l & 15, lk = (l >> 4) * 8;

  f32x4 acc[8][2];
  #pragma unroll
  for (int m = 0; m < 8; ++m) { acc[m][0] = (f32x4){0.f,0.f,0.f,0.f}; acc[m][1] = (f32x4){0.f,0.f,0.f,0.f}; }

  for (int kc = 0; kc < 16; ++kc) {
    int k = kc * 32 + lk;
    f16x8 bf[2];
    #pragma unroll
    for (int n = 0; n < 2; ++n) {
      int r = n * 16 + lr;
      bf[n] = *(const f16x8*)(&vpcH[r * 512 + (((k >> 3) ^ (r & 7))) * 8]);
    }
    #pragma unroll
    for (int m = 0; m < 8; ++m) {
      int c = w * 128 + m * 16 + lr;
      f16x8 af = *(const f16x8*)(WgH + (size_t)c * 512 + k);
      acc[m][0] = __builtin_amdgcn_mfma_f32_16x16x32_f16(af, bf[0], acc[m][0], 0, 0, 0);
      acc[m][1] = __builtin_amdgcn_mfma_f32_16x16x32_f16(af, bf[1], acc[m][1], 0, 0, 0);
    }
  }

  f16x4 xq[8][2];
  #pragma unroll
  for (int m = 0; m < 8; ++m) {
    int c0 = w * 128 + m * 16 + (l >> 4) * 4;
    #pragma unroll
    for (int n = 0; n < 2; ++n) {
      int r = n * 16 + lr;
      int ea = r * 512 + (((c0 >> 3) ^ (r & 7))) * 8 + (c0 & 7);
      f16x4 vq = *(const f16x4*)(&vpcH[ea]);
      f16x4 xo;
      #pragma unroll
      for (int j = 0; j < 4; ++j)
        xo[j] = (_Float16)(sigm(acc[m][n][j]) * (float)vq[j]);
      xq[m][n] = xo;
    }
  }
  __syncthreads();
  #pragma unroll
  for (int m = 0; m < 8; ++m) {
    int c0 = w * 128 + m * 16 + (l >> 4) * 4;
    #pragma unroll
    for (int n = 0; n < 2; ++n) {
      int r = n * 16 + lr;
      int ea = r * 512 + (((c0 >> 3) ^ (r & 7))) * 8 + (c0 & 7);
      *(f16x4*)(&vpcH[ea]) = xq[m][n];
    }
  }
  __syncthreads();

  f32x4 gacc[6][2];
  #pragma unroll
  for (int m = 0; m < 6; ++m) { gacc[m][0] = (f32x4){0.f,0.f,0.f,0.f}; gacc[m][1] = (f32x4){0.f,0.f,0.f,0.f}; }

  for (int kc = 0; kc < 16; ++kc) {
    int k = kc * 32 + lk;
    f16x8 bf[2];
    #pragma unroll
    for (int n = 0; n < 2; ++n) {
      int r = n * 16 + lr;
      bf[n] = *(const f16x8*)(&vpcH[r * 512 + (((k >> 3) ^ (r & 7))) * 8]);
    }
    #pragma unroll
    for (int m = 0; m < 6; ++m) {
      int c = w * 96 + m * 16 + lr;
      f16x8 af = *(const f16x8*)(WihH + (size_t)c * 512 + k);
      gacc[m][0] = __builtin_amdgcn_mfma_f32_16x16x32_f16(af, bf[0], gacc[m][0], 0, 0, 0);
      gacc[m][1] = __builtin_amdgcn_mfma_f32_16x16x32_f16(af, bf[1], gacc[m][1], 0, 0, 0);
    }
  }

  float* gig = ws + OFF_GI;
  #pragma unroll
  for (int m = 0; m < 6; ++m) {
    int c0 = w * 96 + m * 16 + (l >> 4) * 4;
    float4 bq = *(const float4*)(bih + c0);
    #pragma unroll
    for (int n = 0; n < 2; ++n) {
      int r = n * 16 + lr;
      float4 o;
      o.x = gacc[m][n][0] + bq.x;
      o.y = gacc[m][n][1] + bq.y;
      o.z = gacc[m][n][2] + bq.z;
      o.w = gacc[m][n][3] + bq.w;
      *(float4*)(gig + ((size_t)b * SS + t0 + r) * D3 + c0) = o;
    }
  }
}

// ---------------- K4: GRU scan, 384 threads: one W_hh row per thread ----------------
// 2-deep software-pipelined gi prefetch (A/B named register sets), 4-way split
// accumulator chains, register-resident W_hh row, broadcast h via LDS.
__global__ __launch_bounds__(384) void k4_scan(const float* __restrict__ whh,
                                               const float* __restrict__ bhh,
                                               const int* __restrict__ lens,
                                               const float* __restrict__ ws,
                                               float* __restrict__ out) {
  int bid = blockIdx.x;
  int b = bid & 31, dir = bid >> 5;
  int len = lens[b];
  int tid = threadIdx.x;            // 0..383, row of W_hh
  const float* gi = ws + OFF_GI + (size_t)b * SS * D3;

  // register-resident weight row (f16 pairs): 64 VGPRs
  h2_t wr[64];
  {
    const float* wrow = whh + (size_t)tid * HH;
    #pragma unroll
    for (int k = 0; k < 64; ++k)
      wr[k] = h2_t{(_Float16)wrow[2 * k], (_Float16)wrow[2 * k + 1]};
  }
  float bh = bhh[tid];

  __shared__ __align__(16) _Float16 hbuf[128];
  __shared__ float gsum[D3];
  if (tid < 128) hbuf[tid] = (_Float16)0.0f;
  float h_own = 0.0f;

  // preload gi for t=0 (A) and t=1 (B)   (len >= 256 always)
  float gA0 = 0.f, gA1 = 0.f, gA2 = 0.f, gB0 = 0.f, gB1 = 0.f, gB2 = 0.f;
  if (tid < 128) {
    int tg0 = dir ? (len - 1) : 0;
    const float* g0 = gi + (size_t)tg0 * D3;
    gA0 = g0[tid]; gA1 = g0[tid + 128]; gA2 = g0[tid + 256];
    int tg1 = dir ? (len - 2) : 1;
    const float* g1 = gi + (size_t)tg1 * D3;
    gB0 = g1[tid]; gB1 = g1[tid + 128]; gB2 = g1[tid + 256];
  }
  __syncthreads();

  float* outb = out + (size_t)b * SS * D2 + dir * HH;

#define K4_DOT() do {                                                          \
    const f16x8* hb8 = (const f16x8*)hbuf;                                     \
    float c0 = 0.f, c1 = 0.f, c2 = 0.f, c3 = 0.f;                              \
    _Pragma("unroll")                                                          \
    for (int k8 = 0; k8 < 16; ++k8) {                                          \
      f16x8 hv = hb8[k8];                                                      \
      c0 = __builtin_amdgcn_fdot2(__builtin_shufflevector(hv, hv, 0, 1),       \
                                  wr[4 * k8 + 0], c0, false);                  \
      c1 = __builtin_amdgcn_fdot2(__builtin_shufflevector(hv, hv, 2, 3),       \
                                  wr[4 * k8 + 1], c1, false);                  \
      c2 = __builtin_amdgcn_fdot2(__builtin_shufflevector(hv, hv, 4, 5),       \
                                  wr[4 * k8 + 2], c2, false);                  \
      c3 = __builtin_amdgcn_fdot2(__builtin_shufflevector(hv, hv, 6, 7),       \
                                  wr[4 * k8 + 3], c3, false);                  \
    }                                                                          \
    gsum[tid] = ((c0 + c1) + (c2 + c3)) + bh;                                  \
  } while (0)

#define K4_COMBINE(gx0, gx1, gx2, tstep) do {                                  \
    if (tid < 128) {                                                           \
      float r = sigm((gx0) + gsum[tid]);                                       \
      float z = sigm((gx1) + gsum[tid + 128]);                                 \
      float n = fast_tanh(fmaf(r, gsum[tid + 256], (gx2)));                    \
      float hn = (1.0f - z) * n + z * h_own;                                   \
      h_own = hn;                                                              \
      outb[(size_t)(tstep) * D2 + tid] = hn;                                   \
      hbuf[tid] = (_Float16)hn;                                                \
    }                                                                          \
  } while (0)

#define K4_PREFETCH(gx0, gx1, gx2, tnext) do {                                 \
    if (tid < 128) {                                                           \
      int tp = (tnext) < len ? (tnext) : (len - 1);                            \
      int tgp = dir ? (len - 1 - tp) : tp;                                     \
      const float* gp = gi + (size_t)tgp * D3;                                 \
      gx0 = gp[tid]; gx1 = gp[tid + 128]; gx2 = gp[tid + 256];                 \
    }                                                                          \
  } while (0)

  int t = 0;
  while (t + 1 < len) {
    // step t (A)
    K4_DOT();
    __syncthreads();
    K4_COMBINE(gA0, gA1, gA2, t);
    K4_PREFETCH(gA0, gA1, gA2, t + 2);
    __syncthreads();
    // step t+1 (B)
    K4_DOT();
    __syncthreads();
    K4_COMBINE(gB0, gB1, gB2, t + 1);
    K4_PREFETCH(gB0, gB1, gB2, t + 3);
    __syncthreads();
    t += 2;
  }
  if (t < len) {
    K4_DOT();
    __syncthreads();
    K4_COMBINE(gA0, gA1, gA2, t);
  }
#undef K4_DOT
#undef K4_COMBINE
#undef K4_PREFETCH
}

extern "C" void kernel_launch(void* const* d_in, const int* in_sizes, int n_in,
                              void* d_out, int out_size, void* d_ws, size_t ws_size,
                              hipStream_t stream) {
  const float* vp   = (const float*)d_in[0];
  const int*   lens = (const int*)d_in[1];
  const float* Wvp  = (const float*)d_in[2];
  const float* Wvpt = (const float*)d_in[3];
  const float* wvt  = (const float*)d_in[4];
  const float* Wg   = (const float*)d_in[5];
  const float* Wih  = (const float*)d_in[6];
  const float* Whh  = (const float*)d_in[7];
  const float* bih  = (const float*)d_in[8];
  const float* bhh  = (const float*)d_in[9];
  float* out = (float*)d_out;
  float* ws  = (float*)d_ws;

  hipMemsetAsync(d_out, 0, (size_t)out_size * sizeof(float), stream);

  k0_prep<<<2048, 256, 0, stream>>>(Wg, Wih, Wvp, Wvpt, ws);
  k1_keyq<<<BB * SS / 64, 256, 0, stream>>>(vp, ws);
  k2_attn<<<dim3(SS / 16, BB), 256, 0, stream>>>(vp, lens, wvt, ws);
  k3_gates<<<dim3(SS / 32, BB), 256, 0, stream>>>(vp, lens, bih, ws);
  k4_scan<<<64, 384, 0, stream>>>(Whh, bhh, lens, ws, out);
}

// Round 5
// 573.216 us; speedup vs baseline: 2.1076x; 1.3106x over previous
//
#include <hip/hip_runtime.h>
#include <hip/hip_fp16.h>

#define BB 32
#define SS 512
#define HH 128
#define D2 256
#define D3 384
#define D4 512

// ws layout (float offsets)
#define OFF_TK  0                       // Ek = exp(2*keyp) TRANSPOSED [B][H][S] f32
#define OFF_TQ  (OFF_TK + BB*SS*HH)     // Eq = exp(2*q)    [B][S][H] f32
#define OFF_CT  (OFF_TQ + BB*SS*HH)     // context   [B][S][2H] f32
#define OFF_GI  (OFF_CT + BB*SS*D2)     // gi        [B][S][3H] f32
#define OFF_F16 (OFF_GI + BB*SS*D3)     // f16 weight region below (element offsets)
#define F16_WG  0                       // Wg  f16 [512][512] row-major (as given)
#define F16_WIH (F16_WG + D4*D4)        // Wih f16 [384][512]
#define F16_W2  (F16_WIH + D3*D4)       // [WvP;WvPt] f16 [256][256]

typedef _Float16 f16x8 __attribute__((ext_vector_type(8)));
typedef _Float16 f16x4 __attribute__((ext_vector_type(4)));
typedef float    f32x4 __attribute__((ext_vector_type(4)));
typedef _Float16 h2_t  __attribute__((ext_vector_type(2)));

__device__ __forceinline__ float fast_tanh(float x) {
  float ax = fabsf(x);
  float e  = __expf(-2.0f * ax);
  float t  = __fdividef(1.0f - e, 1.0f + e);
  return x < 0.0f ? -t : t;
}
__device__ __forceinline__ float sigm(float x) {
  return __fdividef(1.0f, 1.0f + __expf(-x));
}

// ---------------- K0: convert weights to f16 in ws ----------------
__global__ __launch_bounds__(256) void k0_prep(
    const float* __restrict__ Wg, const float* __restrict__ Wih,
    const float* __restrict__ Wvp, const float* __restrict__ Wvpt,
    float* __restrict__ ws) {
  int i = blockIdx.x * 256 + threadIdx.x;
  _Float16* f16b = (_Float16*)(ws + OFF_F16);
  if (i < D4 * D4) {
    f16b[F16_WG + i] = (_Float16)Wg[i];
  } else if (i < D4 * D4 + D3 * D4) {
    int j = i - D4 * D4;
    f16b[F16_WIH + j] = (_Float16)Wih[j];
  } else {
    int j = i - D4 * D4 - D3 * D4;   // < 65536
    f16b[F16_W2 + j] = (_Float16)(j < HH * D2 ? Wvp[j] : Wvpt[j - HH * D2]);
  }
}

// ---------------- K1: Ek^T / Eq = exp(2 * ([WvP;WvPt] . vp^T)) via MFMA ----------------
__global__ __launch_bounds__(256, 2) void k1_keyq(const float* __restrict__ vp,
                                                  float* __restrict__ ws) {
  __shared__ __align__(16) _Float16 vpH[64 * 256];
  int tid = threadIdx.x;
  int rows0 = blockIdx.x * 64;

  #pragma unroll
  for (int i = 0; i < 8; ++i) {
    int u = tid + i * 256;
    int r = u >> 5, c8 = u & 31;
    const float* src = vp + (size_t)(rows0 + r) * D2 + c8 * 8;
    float4 a = *(const float4*)src;
    float4 b = *(const float4*)(src + 4);
    f16x8 h;
    h[0]=(_Float16)a.x; h[1]=(_Float16)a.y; h[2]=(_Float16)a.z; h[3]=(_Float16)a.w;
    h[4]=(_Float16)b.x; h[5]=(_Float16)b.y; h[6]=(_Float16)b.z; h[7]=(_Float16)b.w;
    *(f16x8*)(&vpH[r * 256 + (c8 ^ (r & 7)) * 8]) = h;
  }
  __syncthreads();

  const _Float16* W2 = (const _Float16*)(ws + OFF_F16) + F16_W2;
  int w = tid >> 6, l = tid & 63;
  int lr = l & 15, lk = (l >> 4) * 8;

  f32x4 acc[4][4];
  #pragma unroll
  for (int m = 0; m < 4; ++m)
    #pragma unroll
    for (int n = 0; n < 4; ++n) acc[m][n] = (f32x4){0.f, 0.f, 0.f, 0.f};

  for (int kc = 0; kc < 8; ++kc) {
    int k = kc * 32 + lk;
    f16x8 bf[4];
    #pragma unroll
    for (int n = 0; n < 4; ++n) {
      int r = n * 16 + lr;
      bf[n] = *(const f16x8*)(&vpH[r * 256 + (((k >> 3) ^ (r & 7))) * 8]);
    }
    #pragma unroll
    for (int m = 0; m < 4; ++m) {
      int c = w * 64 + m * 16 + lr;
      f16x8 af = *(const f16x8*)(W2 + (size_t)c * 256 + k);
      #pragma unroll
      for (int n = 0; n < 4; ++n)
        acc[m][n] = __builtin_amdgcn_mfma_f32_16x16x32_f16(af, bf[n], acc[m][n], 0, 0, 0);
    }
  }

  int b = rows0 >> 9;          // batch
  int s0 = rows0 & 511;        // s offset within batch
  float* ekT = ws + OFF_TK + (size_t)b * HH * SS;
  float* eqp = ws + OFF_TQ + (size_t)b * SS * HH;
  #pragma unroll
  for (int m = 0; m < 4; ++m) {
    int c0 = w * 64 + m * 16 + (l >> 4) * 4;
    #pragma unroll
    for (int n = 0; n < 4; ++n) {
      int s = s0 + n * 16 + lr;
      float v[4];
      #pragma unroll
      for (int j = 0; j < 4; ++j) {
        float z = fminf(fmaxf(2.0f * acc[m][n][j], -60.0f), 60.0f);
        v[j] = __expf(z);
      }
      if (c0 < HH) {
        // Ek transposed: [h][s]
        #pragma unroll
        for (int j = 0; j < 4; ++j)
          ekT[(size_t)(c0 + j) * SS + s] = v[j];
      } else {
        float4 o; o.x = v[0]; o.y = v[1]; o.z = v[2]; o.w = v[3];
        *(float4*)(eqp + (size_t)s * HH + (c0 - HH)) = o;
      }
    }
  }
}

// ---------------- K2: logits via exp-form tanh + softmax + ct ----------------
// 1-D grid 1024 blocks: bid = [t:5][q:2][xcd:3]; all 32 t-tiles of batch b
// share one XCD (b = xcd*4+q keeps bid%8 constant per b).
__global__ __launch_bounds__(256) void k2_attn(const float* __restrict__ vp,
                                               const int* __restrict__ lens,
                                               const float* __restrict__ wvt,
                                               float* __restrict__ ws) {
  int bid = blockIdx.x;                 // 0..1023
  int b  = (bid & 7) * 4 + ((bid >> 3) & 3);
  int t0 = (bid >> 5) * 16;             // 0..496
  int len = lens[b];
  if (t0 >= len) return;
  int nt = min(16, len - t0);

  __shared__ float L[16][SS];           // 32KB
  __shared__ float Eqs[16][HH];         // 8KB
  __shared__ float inv_sum[16];

  int tid = threadIdx.x;
  const float* EkT = ws + OFF_TK + (size_t)b * HH * SS;
  const float* Eq  = ws + OFF_TQ + (size_t)b * SS * HH;

  for (int idx = tid; idx < 16 * HH; idx += 256) {
    int i = idx >> 7, h = idx & 127;
    Eqs[i][h] = Eq[(size_t)(t0 + i) * HH + h];
  }
  __syncthreads();

  // logits: tanh(k+q) = 1 - 2/(Ek*Eq+1); softmax shift-invariance drops the
  // constant sum(w) term -> L = -2 * sum_h w_h * rcp(Ek*Eq+1)
  for (int sc = 0; sc < 2; ++sc) {
    int s = tid + sc * 256;
    if (s < len) {
      float acc[16] = {};
      for (int h4 = 0; h4 < 32; ++h4) {
        float k0 = EkT[(size_t)(h4 * 4 + 0) * SS + s];
        float k1 = EkT[(size_t)(h4 * 4 + 1) * SS + s];
        float k2v = EkT[(size_t)(h4 * 4 + 2) * SS + s];
        float k3 = EkT[(size_t)(h4 * 4 + 3) * SS + s];
        const float4 w4 = *(const float4*)(wvt + h4 * 4);
        #pragma unroll
        for (int t = 0; t < 16; ++t) {
          const float4 q4 = *(const float4*)(&Eqs[t][h4 * 4]);
          float r0 = __builtin_amdgcn_rcpf(fmaf(k0, q4.x, 1.0f));
          float r1 = __builtin_amdgcn_rcpf(fmaf(k1, q4.y, 1.0f));
          float r2 = __builtin_amdgcn_rcpf(fmaf(k2v, q4.z, 1.0f));
          float r3 = __builtin_amdgcn_rcpf(fmaf(k3, q4.w, 1.0f));
          float a = acc[t];
          a = fmaf(w4.x, r0, a);
          a = fmaf(w4.y, r1, a);
          a = fmaf(w4.z, r2, a);
          a = fmaf(w4.w, r3, a);
          acc[t] = a;
        }
      }
      #pragma unroll
      for (int t = 0; t < 16; ++t) L[t][s] = -2.0f * acc[t];
    }
  }
  __syncthreads();

  // softmax (store unnormalized exp; denominators in inv_sum)
  {
    int w = tid >> 6, lane = tid & 63;
    for (int ii = 0; ii < 4; ++ii) {
      int i = w + ii * 4;
      if (i < nt) {
        float m = -1e30f;
        for (int s = lane; s < len; s += 64) m = fmaxf(m, L[i][s]);
        #pragma unroll
        for (int off = 32; off > 0; off >>= 1) m = fmaxf(m, __shfl_xor(m, off));
        float sm = 0.0f;
        for (int s = lane; s < len; s += 64) {
          float e = __expf(L[i][s] - m);
          L[i][s] = e;
          sm += e;
        }
        #pragma unroll
        for (int off = 32; off > 0; off >>= 1) sm += __shfl_xor(sm, off);
        if (lane == 0) inv_sum[i] = __fdividef(1.0f, sm);
      }
    }
  }
  __syncthreads();

  // ct[t][d] = sum_s p[t][s] * vp[b][s][d]   (vp direct from L2, no LDS staging)
  int d4 = (tid & 63) * 4;
  int tg = tid >> 6;
  float4 acc4[4] = {};
  const float* vpb = vp + (size_t)b * SS * D2;
  int s = 0;
  for (; s + 4 <= len; s += 4) {
    #pragma unroll
    for (int u = 0; u < 4; ++u) {
      float4 v4 = *(const float4*)(vpb + (size_t)(s + u) * D2 + d4);
      #pragma unroll
      for (int j = 0; j < 4; ++j) {
        float p = L[tg * 4 + j][s + u];
        acc4[j].x = fmaf(p, v4.x, acc4[j].x);
        acc4[j].y = fmaf(p, v4.y, acc4[j].y);
        acc4[j].z = fmaf(p, v4.z, acc4[j].z);
        acc4[j].w = fmaf(p, v4.w, acc4[j].w);
      }
    }
  }
  for (; s < len; ++s) {
    float4 v4 = *(const float4*)(vpb + (size_t)s * D2 + d4);
    #pragma unroll
    for (int j = 0; j < 4; ++j) {
      float p = L[tg * 4 + j][s];
      acc4[j].x = fmaf(p, v4.x, acc4[j].x);
      acc4[j].y = fmaf(p, v4.y, acc4[j].y);
      acc4[j].z = fmaf(p, v4.z, acc4[j].z);
      acc4[j].w = fmaf(p, v4.w, acc4[j].w);
    }
  }
  float* ctg = ws + OFF_CT + ((size_t)b * SS + t0) * D2;
  #pragma unroll
  for (int j = 0; j < 4; ++j) {
    int t = tg * 4 + j;
    if (t < nt) {
      float is = inv_sum[t];
      float4 o;
      o.x = acc4[j].x * is; o.y = acc4[j].y * is;
      o.z = acc4[j].z * is; o.w = acc4[j].w * is;
      *(float4*)(ctg + (size_t)t * D2 + d4) = o;
    }
  }
}

// ---------------- K3: gt' = Wg.vpc^T -> xin (in-place LDS) -> gi' = Wih.xin^T ----------------
__global__ __launch_bounds__(256, 2) void k3_gates(const float* __restrict__ vp,
                                                   const int* __restrict__ lens,
                                                   const float* __restrict__ bih,
                                                   float* __restrict__ ws) {
  int b = blockIdx.y;
  int len = lens[b];
  int t0 = blockIdx.x * 32;
  if (t0 >= len) return;

  __shared__ __align__(16) _Float16 vpcH[32 * 512];
  int tid = threadIdx.x;
  const float* ct = ws + OFF_CT;

  #pragma unroll
  for (int i = 0; i < 8; ++i) {
    int u = tid + i * 256;
    int r = u >> 6, c8 = u & 63;
    int c = c8 * 8;
    const float* src = (c < D2) ? (vp + ((size_t)b * SS + t0 + r) * D2 + c)
                                : (ct + ((size_t)b * SS + t0 + r) * D2 + (c - D2));
    float4 a = *(const float4*)src;
    float4 bb = *(const float4*)(src + 4);
    f16x8 h;
    h[0]=(_Float16)a.x;  h[1]=(_Float16)a.y;  h[2]=(_Float16)a.z;  h[3]=(_Float16)a.w;
    h[4]=(_Float16)bb.x; h[5]=(_Float16)bb.y; h[6]=(_Float16)bb.z; h[7]=(_Float16)bb.w;
    *(f16x8*)(&vpcH[r * 512 + (c8 ^ (r & 7)) * 8]) = h;
  }
  __syncthreads();

  const _Float16* WgH  = (const _Float16*)(ws + OFF_F16) + F16_WG;
  const _Float16* WihH = (const _Float16*)(ws + OFF_F16) + F16_WIH;
  int w = tid >> 6, l = tid & 63;
  int lr = l & 15, lk = (l >> 4) * 8;

  f32x4 acc[8][2];
  #pragma unroll
  for (int m = 0; m < 8; ++m) { acc[m][0] = (f32x4){0.f,0.f,0.f,0.f}; acc[m][1] = (f32x4){0.f,0.f,0.f,0.f}; }

  for (int kc = 0; kc < 16; ++kc) {
    int k = kc * 32 + lk;
    f16x8 bf[2];
    #pragma unroll
    for (int n = 0; n < 2; ++n) {
      int r = n * 16 + lr;
      bf[n] = *(const f16x8*)(&vpcH[r * 512 + (((k >> 3) ^ (r & 7))) * 8]);
    }
    #pragma unroll
    for (int m = 0; m < 8; ++m) {
      int c = w * 128 + m * 16 + lr;
      f16x8 af = *(const f16x8*)(WgH + (size_t)c * 512 + k);
      acc[m][0] = __builtin_amdgcn_mfma_f32_16x16x32_f16(af, bf[0], acc[m][0], 0, 0, 0);
      acc[m][1] = __builtin_amdgcn_mfma_f32_16x16x32_f16(af, bf[1], acc[m][1], 0, 0, 0);
    }
  }

  f16x4 xq[8][2];
  #pragma unroll
  for (int m = 0; m < 8; ++m) {
    int c0 = w * 128 + m * 16 + (l >> 4) * 4;
    #pragma unroll
    for (int n = 0; n < 2; ++n) {
      int r = n * 16 + lr;
      int ea = r * 512 + (((c0 >> 3) ^ (r & 7))) * 8 + (c0 & 7);
      f16x4 vq = *(const f16x4*)(&vpcH[ea]);
      f16x4 xo;
      #pragma unroll
      for (int j = 0; j < 4; ++j)
        xo[j] = (_Float16)(sigm(acc[m][n][j]) * (float)vq[j]);
      xq[m][n] = xo;
    }
  }
  __syncthreads();
  #pragma unroll
  for (int m = 0; m < 8; ++m) {
    int c0 = w * 128 + m * 16 + (l >> 4) * 4;
    #pragma unroll
    for (int n = 0; n < 2; ++n) {
      int r = n * 16 + lr;
      int ea = r * 512 + (((c0 >> 3) ^ (r & 7))) * 8 + (c0 & 7);
      *(f16x4*)(&vpcH[ea]) = xq[m][n];
    }
  }
  __syncthreads();

  f32x4 gacc[6][2];
  #pragma unroll
  for (int m = 0; m < 6; ++m) { gacc[m][0] = (f32x4){0.f,0.f,0.f,0.f}; gacc[m][1] = (f32x4){0.f,0.f,0.f,0.f}; }

  for (int kc = 0; kc < 16; ++kc) {
    int k = kc * 32 + lk;
    f16x8 bf[2];
    #pragma unroll
    for (int n = 0; n < 2; ++n) {
      int r = n * 16 + lr;
      bf[n] = *(const f16x8*)(&vpcH[r * 512 + (((k >> 3) ^ (r & 7))) * 8]);
    }
    #pragma unroll
    for (int m = 0; m < 6; ++m) {
      int c = w * 96 + m * 16 + lr;
      f16x8 af = *(const f16x8*)(WihH + (size_t)c * 512 + k);
      gacc[m][0] = __builtin_amdgcn_mfma_f32_16x16x32_f16(af, bf[0], gacc[m][0], 0, 0, 0);
      gacc[m][1] = __builtin_amdgcn_mfma_f32_16x16x32_f16(af, bf[1], gacc[m][1], 0, 0, 0);
    }
  }

  float* gig = ws + OFF_GI;
  #pragma unroll
  for (int m = 0; m < 6; ++m) {
    int c0 = w * 96 + m * 16 + (l >> 4) * 4;
    float4 bq = *(const float4*)(bih + c0);
    #pragma unroll
    for (int n = 0; n < 2; ++n) {
      int r = n * 16 + lr;
      float4 o;
      o.x = gacc[m][n][0] + bq.x;
      o.y = gacc[m][n][1] + bq.y;
      o.z = gacc[m][n][2] + bq.z;
      o.w = gacc[m][n][3] + bq.w;
      *(float4*)(gig + ((size_t)b * SS + t0 + r) * D3 + c0) = o;
    }
  }
}

// ---------------- K4: GRU scan, raw barriers (no vmcnt drain), depth-4 prefetch ----------------
__global__ __launch_bounds__(384) void k4_scan(const float* __restrict__ whh,
                                               const float* __restrict__ bhh,
                                               const int* __restrict__ lens,
                                               const float* __restrict__ ws,
                                               float* __restrict__ out) {
  int bid = blockIdx.x;
  // XCD-pair swizzle: fwd/rev of same b land on the same XCD (bid%8 preserved)
  int xcd = bid & 7, dir = (bid >> 3) & 1, q = bid >> 4;
  int b = xcd * 4 + q;
  int len = lens[b];
  int tid = threadIdx.x;            // 0..383, row of W_hh
  const float* gi = ws + OFF_GI + (size_t)b * SS * D3;

  h2_t wr[64];
  {
    const float* wrow = whh + (size_t)tid * HH;
    #pragma unroll
    for (int k = 0; k < 64; ++k)
      wr[k] = h2_t{(_Float16)wrow[2 * k], (_Float16)wrow[2 * k + 1]};
  }
  float bh = bhh[tid];

  __shared__ __align__(16) _Float16 hbuf[128];
  __shared__ float gsum[D3];
  if (tid < 128) hbuf[tid] = (_Float16)0.0f;
  float h_own = 0.0f;

  float* outb = out + (size_t)b * SS * D2 + dir * HH;

#define K4_BAR() do {                                                          \
    asm volatile("s_waitcnt lgkmcnt(0)" ::: "memory");                         \
    __builtin_amdgcn_s_barrier();                                              \
    __builtin_amdgcn_sched_barrier(0);                                         \
  } while (0)

#define K4_PF(gx0, gx1, gx2, tnext) do {                                       \
    if (tid < 128) {                                                           \
      int tp = (tnext) < len ? (tnext) : (len - 1);                            \
      int tgp = dir ? (len - 1 - tp) : tp;                                     \
      const float* gp = gi + (size_t)tgp * D3;                                 \
      gx0 = gp[tid]; gx1 = gp[tid + 128]; gx2 = gp[tid + 256];                 \
    }                                                                          \
  } while (0)

#define K4_DOT() do {                                                          \
    const f16x8* hb8 = (const f16x8*)hbuf;                                     \
    float c0 = 0.f, c1 = 0.f, c2 = 0.f, c3 = 0.f;                              \
    _Pragma("unroll")                                                          \
    for (int k8 = 0; k8 < 16; ++k8) {                                          \
      f16x8 hv = hb8[k8];                                                      \
      c0 = __builtin_amdgcn_fdot2(__builtin_shufflevector(hv, hv, 0, 1),       \
                                  wr[4 * k8 + 0], c0, false);                  \
      c1 = __builtin_amdgcn_fdot2(__builtin_shufflevector(hv, hv, 2, 3),       \
                                  wr[4 * k8 + 1], c1, false);                  \
      c2 = __builtin_amdgcn_fdot2(__builtin_shufflevector(hv, hv, 4, 5),       \
                                  wr[4 * k8 + 2], c2, false);                  \
      c3 = __builtin_amdgcn_fdot2(__builtin_shufflevector(hv, hv, 6, 7),       \
                                  wr[4 * k8 + 3], c3, false);                  \
    }                                                                          \
    gsum[tid] = ((c0 + c1) + (c2 + c3)) + bh;                                  \
  } while (0)

#define K4_COMBINE(gx0, gx1, gx2, tstep) do {                                  \
    if (tid < 128) {                                                           \
      float r = sigm((gx0) + gsum[tid]);                                       \
      float z = sigm((gx1) + gsum[tid + 128]);                                 \
      float n = fast_tanh(fmaf(r, gsum[tid + 256], (gx2)));                    \
      float hn = (1.0f - z) * n + z * h_own;                                   \
      h_own = hn;                                                              \
      outb[(size_t)(tstep) * D2 + tid] = hn;                                   \
      hbuf[tid] = (_Float16)hn;                                                \
    }                                                                          \
  } while (0)

#define K4_STEP(gx0, gx1, gx2, tstep) do {                                     \
    K4_DOT();                                                                  \
    K4_BAR();                                                                  \
    K4_COMBINE(gx0, gx1, gx2, (tstep));                                        \
    K4_PF(gx0, gx1, gx2, (tstep) + 4);                                         \
    K4_BAR();                                                                  \
  } while (0)

  // prologue: prefetch t=0..3 (len >= 256 always)
  float gA0 = 0.f, gA1 = 0.f, gA2 = 0.f;
  float gB0 = 0.f, gB1 = 0.f, gB2 = 0.f;
  float gC0 = 0.f, gC1 = 0.f, gC2 = 0.f;
  float gD0 = 0.f, gD1 = 0.f, gD2 = 0.f;
  K4_PF(gA0, gA1, gA2, 0);
  K4_PF(gB0, gB1, gB2, 1);
  K4_PF(gC0, gC1, gC2, 2);
  K4_PF(gD0, gD1, gD2, 3);
  K4_BAR();   // hbuf init visible; global prefetches stay in flight

  int t = 0;
  while (t + 3 < len) {
    K4_STEP(gA0, gA1, gA2, t);
    K4_STEP(gB0, gB1, gB2, t + 1);
    K4_STEP(gC0, gC1, gC2, t + 2);
    K4_STEP(gD0, gD1, gD2, t + 3);
    t += 4;
  }
  if (t < len)     K4_STEP(gA0, gA1, gA2, t);
  if (t + 1 < len) K4_STEP(gB0, gB1, gB2, t + 1);
  if (t + 2 < len) K4_STEP(gC0, gC1, gC2, t + 2);

#undef K4_STEP
#undef K4_COMBINE
#undef K4_DOT
#undef K4_PF
#undef K4_BAR
}

extern "C" void kernel_launch(void* const* d_in, const int* in_sizes, int n_in,
                              void* d_out, int out_size, void* d_ws, size_t ws_size,
                              hipStream_t stream) {
  const float* vp   = (const float*)d_in[0];
  const int*   lens = (const int*)d_in[1];
  const float* Wvp  = (const float*)d_in[2];
  const float* Wvpt = (const float*)d_in[3];
  const float* wvt  = (const float*)d_in[4];
  const float* Wg   = (const float*)d_in[5];
  const float* Wih  = (const float*)d_in[6];
  const float* Whh  = (const float*)d_in[7];
  const float* bih  = (const float*)d_in[8];
  const float* bhh  = (const float*)d_in[9];
  float* out = (float*)d_out;
  float* ws  = (float*)d_ws;

  hipMemsetAsync(d_out, 0, (size_t)out_size * sizeof(float), stream);

  k0_prep<<<2048, 256, 0, stream>>>(Wg, Wih, Wvp, Wvpt, ws);
  k1_keyq<<<BB * SS / 64, 256, 0, stream>>>(vp, ws);
  k2_attn<<<1024, 256, 0, stream>>>(vp, lens, wvt, ws);
  k3_gates<<<dim3(SS / 32, BB), 256, 0, stream>>>(vp, lens, bih, ws);
  k4_scan<<<64, 384, 0, stream>>>(Whh, bhh, lens, ws, out);
}